// Round 10
// baseline (118.703 us; speedup 1.0000x reference)
//
#include <hip/hip_runtime.h>
#include <hip/hip_bf16.h>

#define NN 50000
#define NE 312500
#define FIN 256

typedef __attribute__((ext_vector_type(4))) float f32x4;
typedef __attribute__((ext_vector_type(8))) short bf16x8;
typedef __attribute__((ext_vector_type(4))) unsigned short u16x4;

__device__ __forceinline__ float bf2f(unsigned short u) {
  return __builtin_bit_cast(float, ((unsigned int)u) << 16);
}
__device__ __forceinline__ unsigned short f2bf(float f) {
  return __builtin_bit_cast(unsigned short, __float2bfloat16(f));
}

__global__ void k_hist(const int* __restrict__ Ai, int* __restrict__ deg) {
  int e = blockIdx.x * 256 + threadIdx.x;
  if (e < NE) atomicAdd(&deg[Ai[e]], 1);
}

__global__ void k_scan1(const int* __restrict__ deg, int* __restrict__ incl,
                        int* __restrict__ bsum) {
  __shared__ int sm[256];
  int i = blockIdx.x * 256 + threadIdx.x;
  int v = (i < NN) ? deg[i] : 0;
  sm[threadIdx.x] = v;
  __syncthreads();
  for (int s = 1; s < 256; s <<= 1) {
    int t = (threadIdx.x >= (unsigned)s) ? sm[threadIdx.x - s] : 0;
    __syncthreads();
    sm[threadIdx.x] += t;
    __syncthreads();
  }
  if (i < NN) incl[i] = sm[threadIdx.x];
  if (threadIdx.x == 255) bsum[blockIdx.x] = sm[255];
}

__global__ void k_scan2(int* __restrict__ bsum) {
  __shared__ int sm[256];
  int v = (threadIdx.x < 196) ? bsum[threadIdx.x] : 0;
  sm[threadIdx.x] = v;
  __syncthreads();
  for (int s = 1; s < 256; s <<= 1) {
    int t = (threadIdx.x >= (unsigned)s) ? sm[threadIdx.x - s] : 0;
    __syncthreads();
    sm[threadIdx.x] += t;
    __syncthreads();
  }
  if (threadIdx.x < 196) bsum[threadIdx.x] = sm[threadIdx.x] - v;
}

__global__ void k_scan3(const int* __restrict__ incl, const int* __restrict__ deg,
                        const int* __restrict__ bsum, int* __restrict__ offs,
                        int* __restrict__ cursor) {
  int i = blockIdx.x * 256 + threadIdx.x;
  if (i < NN) {
    int o = incl[i] - deg[i] + bsum[blockIdx.x];
    offs[i] = o;
    cursor[i] = o;
  }
}

__global__ void k_scatter(const int* __restrict__ Ai, const int* __restrict__ Aj,
                          int* __restrict__ cursor, int* __restrict__ edst) {
  int e = blockIdx.x * 256 + threadIdx.x;
  if (e < NE) {
    int p = atomicAdd(&cursor[Ai[e]], 1);
    edst[p] = Aj[e];
  }
}

__device__ __forceinline__ bf16x8 cvt8(const float* p) {
  f32x4 a = *(const f32x4*)p;
  f32x4 c = *(const f32x4*)(p + 4);
  bf16x8 r;
  #pragma unroll
  for (int i = 0; i < 4; ++i) {
    r[i]     = (short)f2bf(a[i]);
    r[i + 4] = (short)f2bf(c[i]);
  }
  return r;
}

// Fused: blocks 0..63 pack W into B-fragment order; blocks 64..259 zero deg.
__global__ __launch_bounds__(256) void k_wz(const float* __restrict__ W,
                                            unsigned short* __restrict__ WbP,
                                            int* __restrict__ deg) {
  if (blockIdx.x >= 64) {
    int i = (blockIdx.x - 64) * 256 + threadIdx.x;
    if (i < 50048) deg[i] = 0;
    return;
  }
  int lane = threadIdx.x & 63, wid = threadIdx.x >> 6;
  int c = blockIdx.x * 4 + wid;           // 256 chunks
  int o16 = c >> 3, kk = c & 7;
  int lr = lane & 15, lk = lane >> 4;
  int o = o16 * 16 + lr;
  int k = kk * 32 + lk * 8;
  const float* src = (o < 256) ? (W + (size_t)o * 512 + k)
                               : (W + (size_t)(o - 256) * 512 + 256 + k);
  *(bf16x8*)(WbP + (size_t)c * 512 + lane * 8) = cvt8(src);
}

// GEMM: Yb[row][q] = bf16( x[row] @ [W1|W2]^T ), q PERMUTED:
// q = h*256 + w*32 + lr*2 + n  <->  true col = h*256 + w*32 + n*16 + lr.
// Grid (1564): block = 32 rows x 512 cols, 512 threads = 8 waves x 2 col16.
// A staged fp32 in FRAG ORDER via global_load_lds (per-lane gather source,
// linear dest, zero staging VALU); cvt to bf16 at ds_read. B = 16 frags
// (64 VGPR) per wave, pinned live via asm. x read once from HBM.
__global__ __launch_bounds__(512, 4) void k_gemm(
    const float* __restrict__ x, const unsigned short* __restrict__ WbP,
    unsigned short* __restrict__ Yb) {
  __shared__ __align__(16) float Af[8192];   // 32KB: 32 chunk-halves x 256 f32
  const int tid = threadIdx.x;
  const int lane = tid & 63, w = tid >> 6;   // 8 waves
  const int lr = lane & 15, lk = lane >> 4;
  const int n0 = blockIdx.x * 32;

  // issue A DMA: 4 chunk-halves per wave (32 x 1KB total)
  #pragma unroll
  for (int i = 0; i < 4; ++i) {
    int idx = w * 4 + i;            // 0..31
    int r16 = idx >> 4;             // 0..1
    int kk = (idx >> 1) & 7;
    int half = idx & 1;
    int g = n0 + r16 * 16 + lr;
    if (g >= NN) g = NN - 1;        // clamp: tail rows guarded at store
    const float* src = x + (size_t)g * FIN + kk * 32 + lk * 8 + half * 4;
    float* dst = Af + ((r16 * 8 + kk) * 2 + half) * 256 + lane * 4;
    __builtin_amdgcn_global_load_lds(
        (const __attribute__((address_space(1))) void*)src,
        (__attribute__((address_space(3))) void*)dst, 16, 0, 0);
  }
  __syncthreads();   // drains DMA; A ready for all waves

  #pragma unroll
  for (int h = 0; h < 2; ++h) {
    // B panel for this phase: 2 col16 x 8 kk = 16 frags = 64 VGPR
    bf16x8 bfr[8][2];
    #pragma unroll
    for (int kk = 0; kk < 8; ++kk)
      #pragma unroll
      for (int n = 0; n < 2; ++n)
        bfr[kk][n] = *(const bf16x8*)(WbP + ((size_t)(h * 16 + w * 2 + n) * 8 + kk) * 512 + lane * 8);
    #pragma unroll
    for (int kk = 0; kk < 8; ++kk)
      #pragma unroll
      for (int n = 0; n < 2; ++n)
        asm volatile("" : "+v"(bfr[kk][n]));   // pin live: no remat/sink

    #pragma unroll
    for (int r = 0; r < 2; ++r) {
      f32x4 acc0 = {0.f, 0.f, 0.f, 0.f}, acc1 = {0.f, 0.f, 0.f, 0.f};
      #pragma unroll
      for (int kk = 0; kk < 8; ++kk) {
        f32x4 lo = *(const f32x4*)(Af + ((r * 8 + kk) * 2 + 0) * 256 + lane * 4);
        f32x4 hi = *(const f32x4*)(Af + ((r * 8 + kk) * 2 + 1) * 256 + lane * 4);
        bf16x8 a;
        #pragma unroll
        for (int i = 0; i < 4; ++i) {
          a[i]     = (short)f2bf(lo[i]);
          a[i + 4] = (short)f2bf(hi[i]);
        }
        acc0 = __builtin_amdgcn_mfma_f32_16x16x32_bf16(a, bfr[kk][0], acc0, 0, 0, 0);
        acc1 = __builtin_amdgcn_mfma_f32_16x16x32_bf16(a, bfr[kk][1], acc1, 0, 0, 0);
      }
      #pragma unroll
      for (int rr = 0; rr < 4; ++rr) {
        int row = n0 + r * 16 + lk * 4 + rr;
        if (row < NN) {
          unsigned int pk = (unsigned int)f2bf(acc0[rr]) |
                            ((unsigned int)f2bf(acc1[rr]) << 16);
          *(unsigned int*)(Yb + (size_t)row * 512 + h * 256 + w * 32 + lr * 2) = pk;
        }
      }
    }
  }
}

// One wave per node: out[n] = deg[n]*(Y1b[n]+b) + sum_{CSR} Y2b[j].
// Yb is column-permuted; accumulate permuted, unpermute via 1KB/wave LDS.
__global__ __launch_bounds__(256) void k_epi(
    const unsigned short* __restrict__ Yb, const int* __restrict__ offs,
    const int* __restrict__ deg, const int* __restrict__ edst,
    const float* __restrict__ bias, float* __restrict__ out) {
  __shared__ float sm[1024];
  int wid = threadIdx.x >> 6;
  int lane = threadIdx.x & 63;
  int n = blockIdx.x * 4 + wid;
  if (n >= NN) return;
  int o = offs[n];
  int c = deg[n];
  const unsigned short* Y2 = Yb + 256 + (size_t)lane * 4;
  f32x4 a0 = {0.f,0.f,0.f,0.f}, a1 = a0, a2 = a0, a3 = a0, a4 = a0, a5 = a0, a6 = a0, a7 = a0;
  int e = 0;
  for (; e + 8 <= c; e += 8) {
    int j0 = edst[o+e],   j1 = edst[o+e+1], j2 = edst[o+e+2], j3 = edst[o+e+3];
    int j4 = edst[o+e+4], j5 = edst[o+e+5], j6 = edst[o+e+6], j7 = edst[o+e+7];
    u16x4 v0 = *(const u16x4*)(Y2 + (size_t)j0 * 512);
    u16x4 v1 = *(const u16x4*)(Y2 + (size_t)j1 * 512);
    u16x4 v2 = *(const u16x4*)(Y2 + (size_t)j2 * 512);
    u16x4 v3 = *(const u16x4*)(Y2 + (size_t)j3 * 512);
    u16x4 v4 = *(const u16x4*)(Y2 + (size_t)j4 * 512);
    u16x4 v5 = *(const u16x4*)(Y2 + (size_t)j5 * 512);
    u16x4 v6 = *(const u16x4*)(Y2 + (size_t)j6 * 512);
    u16x4 v7 = *(const u16x4*)(Y2 + (size_t)j7 * 512);
    #pragma unroll
    for (int i = 0; i < 4; ++i) {
      a0[i] += bf2f(v0[i]); a1[i] += bf2f(v1[i]); a2[i] += bf2f(v2[i]); a3[i] += bf2f(v3[i]);
      a4[i] += bf2f(v4[i]); a5[i] += bf2f(v5[i]); a6[i] += bf2f(v6[i]); a7[i] += bf2f(v7[i]);
    }
  }
  if (e + 4 <= c) {
    int j0 = edst[o+e], j1 = edst[o+e+1], j2 = edst[o+e+2], j3 = edst[o+e+3];
    u16x4 v0 = *(const u16x4*)(Y2 + (size_t)j0 * 512);
    u16x4 v1 = *(const u16x4*)(Y2 + (size_t)j1 * 512);
    u16x4 v2 = *(const u16x4*)(Y2 + (size_t)j2 * 512);
    u16x4 v3 = *(const u16x4*)(Y2 + (size_t)j3 * 512);
    #pragma unroll
    for (int i = 0; i < 4; ++i) {
      a0[i] += bf2f(v0[i]); a1[i] += bf2f(v1[i]); a2[i] += bf2f(v2[i]); a3[i] += bf2f(v3[i]);
    }
    e += 4;
  }
  if (e + 2 <= c) {
    int j0 = edst[o+e], j1 = edst[o+e+1];
    u16x4 v0 = *(const u16x4*)(Y2 + (size_t)j0 * 512);
    u16x4 v1 = *(const u16x4*)(Y2 + (size_t)j1 * 512);
    #pragma unroll
    for (int i = 0; i < 4; ++i) { a0[i] += bf2f(v0[i]); a1[i] += bf2f(v1[i]); }
    e += 2;
  }
  if (e < c) {
    int j0 = edst[o+e];
    u16x4 v0 = *(const u16x4*)(Y2 + (size_t)j0 * 512);
    #pragma unroll
    for (int i = 0; i < 4; ++i) a0[i] += bf2f(v0[i]);
  }
  u16x4 y1 = *(const u16x4*)(Yb + (size_t)n * 512 + lane * 4);
  float dg = (float)c;
  float* Wm = sm + wid * 256;
  #pragma unroll
  for (int i = 0; i < 4; ++i) {
    int p = lane * 4 + i;                                  // permuted pos in half
    int tc = (p & ~31) | ((p & 1) << 4) | ((p >> 1) & 15); // true col in half
    float as = ((a0[i] + a1[i]) + (a2[i] + a3[i])) + ((a4[i] + a5[i]) + (a6[i] + a7[i]));
    Wm[tc] = dg * (bf2f(y1[i]) + bias[tc]) + as;
  }
  asm volatile("s_waitcnt lgkmcnt(0)" ::: "memory");   // wave-lockstep unpermute
  f32x4 res = *(const f32x4*)(Wm + lane * 4);
  __builtin_nontemporal_store(res, (f32x4*)out + (size_t)n * 64 + lane);
}

extern "C" void kernel_launch(void* const* d_in, const int* in_sizes, int n_in,
                              void* d_out, int out_size, void* d_ws, size_t ws_size,
                              hipStream_t stream) {
  const float* x = (const float*)d_in[0];
  const float* W = (const float*)d_in[1];
  const float* b = (const float*)d_in[2];
  const int* Ai = (const int*)d_in[3];
  const int* Aj = (const int*)d_in[4];
  float* out = (float*)d_out;

  int* ip = (int*)d_ws;
  int* deg    = ip;            // 50048 (zeroed by k_wz, padded)
  int* incl   = ip + 50048;
  int* offs   = ip + 100096;
  int* cursor = ip + 150144;
  int* bsum   = ip + 200192;   // 256
  int* edst   = ip + 200448;   // 312576
  unsigned short* WbP = (unsigned short*)(ip + 513024);   // 131072 bf16 = 256KB
  unsigned short* Yb  = (unsigned short*)(ip + 578560);   // 50048*512 bf16 = 51.2MB

  k_wz<<<260, 256, 0, stream>>>(W, WbP, deg);
  k_hist<<<1221, 256, 0, stream>>>(Ai, deg);
  k_scan1<<<196, 256, 0, stream>>>(deg, incl, bsum);
  k_scan2<<<1, 256, 0, stream>>>(bsum);
  k_scan3<<<196, 256, 0, stream>>>(incl, deg, bsum, offs, cursor);
  k_scatter<<<1221, 256, 0, stream>>>(Ai, Aj, cursor, edst);
  k_gemm<<<1564, 512, 0, stream>>>(x, WbP, Yb);
  k_epi<<<12500, 256, 0, stream>>>(Yb, offs, deg, edst, b, out);
}

// Round 11
// 98.629 us; speedup vs baseline: 1.2035x; 1.2035x over previous
//
#include <hip/hip_runtime.h>
#include <hip/hip_bf16.h>

#define NN 50000
#define NE 312500
#define FIN 256
#define NT 1564   // 32-row tiles covering 50048 rows

typedef __attribute__((ext_vector_type(4))) float f32x4;
typedef __attribute__((ext_vector_type(8))) short bf16x8;
typedef __attribute__((ext_vector_type(4))) unsigned short u16x4;

__device__ __forceinline__ float bf2f(unsigned short u) {
  return __builtin_bit_cast(float, ((unsigned int)u) << 16);
}
__device__ __forceinline__ unsigned short f2bf(float f) {
  return __builtin_bit_cast(unsigned short, __float2bfloat16(f));
}

__device__ __forceinline__ bf16x8 cvt8v(f32x4 a, f32x4 b) {
  bf16x8 r;
  #pragma unroll
  for (int i = 0; i < 4; ++i) {
    r[i]     = (short)f2bf(a[i]);
    r[i + 4] = (short)f2bf(b[i]);
  }
  return r;
}

__device__ __forceinline__ bf16x8 cvt8(const float* p) {
  return cvt8v(*(const f32x4*)p, *(const f32x4*)(p + 4));
}

// blocks 0..63: pack W into B-fragment order; blocks 64..259: zero deg.
__global__ __launch_bounds__(256) void k_wz(const float* __restrict__ W,
                                            unsigned short* __restrict__ WbP,
                                            int* __restrict__ deg) {
  if (blockIdx.x >= 64) {
    int i = (blockIdx.x - 64) * 256 + threadIdx.x;
    if (i < 50048) deg[i] = 0;
    return;
  }
  int lane = threadIdx.x & 63, wid = threadIdx.x >> 6;
  int c = blockIdx.x * 4 + wid;           // 256 chunks
  int o16 = c >> 3, kk = c & 7;
  int lr = lane & 15, lk = lane >> 4;
  int o = o16 * 16 + lr;
  int k = kk * 32 + lk * 8;
  const float* src = (o < 256) ? (W + (size_t)o * 512 + k)
                               : (W + (size_t)(o - 256) * 512 + 256 + k);
  *(bf16x8*)(WbP + (size_t)c * 512 + lane * 8) = cvt8(src);
}

// PERSISTENT GEMM + fused hist.
// Grid = 256 blocks x 512 thr (8 waves). Wave w owns cols w*64..+63:
// B-panel = 32 frags (128 regs), loaded ONCE. Tiles of 32 rows, strided
// by 256: cross-tile pipeline {issue loads(t+1) | MFMA(t) | store(t) |
// cvt+ds_write(t+1) | barrier}. A-LDS double-buffered, r8-verified swizzle.
// Yb permuted: within stripe w, col' = lr*4+n <-> true col = n*16+lr.
__global__ __launch_bounds__(512) void k_gemm(
    const float* __restrict__ x, const unsigned short* __restrict__ WbP,
    unsigned short* __restrict__ Yb,
    const int* __restrict__ Ai, int* __restrict__ deg) {
  __shared__ __align__(16) unsigned short A[2][8192];   // 2 x 16KB
  const int tid = threadIdx.x;
  const int lane = tid & 63, w = tid >> 6;
  const int lr = lane & 15, lk = lane >> 4;

  // fused degree histogram (overlaps with B-load/stage latency)
  for (int e = blockIdx.x * 512 + tid; e < NE; e += 256 * 512)
    atomicAdd(&deg[Ai[e]], 1);

  // B panel: 32 frags = 128 regs, loaded once (L2-resident WbP)
  bf16x8 B[8][4];
  #pragma unroll
  for (int kk = 0; kk < 8; ++kk)
    #pragma unroll
    for (int n = 0; n < 4; ++n)
      B[kk][n] = *(const bf16x8*)(WbP + ((size_t)(w * 4 + n) * 8 + kk) * 512 + lane * 8);
  #pragma unroll
  for (int kk = 0; kk < 8; ++kk)
    #pragma unroll
    for (int n = 0; n < 4; ++n)
      asm volatile("" : "+v"(B[kk][n]));   // keep resident (VGPR/AGPR)

  const int row0 = (tid >> 5);          // stage row-in-tile, it=0
  const int seg = tid & 31;             // 8-float k-granule
  const int uoff0 = ((row0 >> 4) * 8 + (seg >> 2)) * 512 +
                    (((((seg & 3) * 16) + (row0 & 15)) * 8) ^ ((seg & 7) << 3));
  const int row1 = 16 + row0;
  const int uoff1 = ((row1 >> 4) * 8 + (seg >> 2)) * 512 +
                    (((((seg & 3) * 16) + (row1 & 15)) * 8) ^ ((seg & 7) << 3));

  int tile = blockIdx.x;
  // prologue: stage first tile into A[0]
  {
    int g0 = tile * 32 + row0; if (g0 > NN - 1) g0 = NN - 1;
    int g1 = tile * 32 + row1; if (g1 > NN - 1) g1 = NN - 1;
    const float* s0 = x + (size_t)g0 * FIN + seg * 8;
    const float* s1 = x + (size_t)g1 * FIN + seg * 8;
    f32x4 a0 = *(const f32x4*)s0, b0 = *(const f32x4*)(s0 + 4);
    f32x4 a1 = *(const f32x4*)s1, b1 = *(const f32x4*)(s1 + 4);
    *(bf16x8*)(&A[0][uoff0]) = cvt8v(a0, b0);
    *(bf16x8*)(&A[0][uoff1]) = cvt8v(a1, b1);
  }
  __syncthreads();

  int p = 0;
  for (; tile < NT; tile += 256) {
    const int nxt = tile + 256;
    const bool hn = (nxt < NT);

    // issue next tile's loads early (hidden under MFMA)
    f32x4 a0, b0, a1, b1;
    if (hn) {
      int g0 = nxt * 32 + row0; if (g0 > NN - 1) g0 = NN - 1;
      int g1 = nxt * 32 + row1; if (g1 > NN - 1) g1 = NN - 1;
      const float* s0 = x + (size_t)g0 * FIN + seg * 8;
      const float* s1 = x + (size_t)g1 * FIN + seg * 8;
      a0 = *(const f32x4*)s0; b0 = *(const f32x4*)(s0 + 4);
      a1 = *(const f32x4*)s1; b1 = *(const f32x4*)(s1 + 4);
    }

    // MFMA over A[p]: 16 ds_read_b128 + 64 MFMA per wave
    f32x4 acc[2][4];
    #pragma unroll
    for (int rg = 0; rg < 2; ++rg)
      #pragma unroll
      for (int n = 0; n < 4; ++n) acc[rg][n] = (f32x4){0.f, 0.f, 0.f, 0.f};
    #pragma unroll
    for (int rg = 0; rg < 2; ++rg) {
      #pragma unroll
      for (int kk = 0; kk < 8; ++kk) {
        bf16x8 af = *(const bf16x8*)(
            &A[p][(rg * 8 + kk) * 512 + ((lane * 8) ^ (((kk & 1) << 5) | (lk << 3)))]);
        #pragma unroll
        for (int n = 0; n < 4; ++n)
          acc[rg][n] = __builtin_amdgcn_mfma_f32_16x16x32_bf16(af, B[kk][n], acc[rg][n], 0, 0, 0);
      }
    }

    // store (Yb padded to 50048 rows -> unguarded)
    #pragma unroll
    for (int rg = 0; rg < 2; ++rg) {
      #pragma unroll
      for (int rr = 0; rr < 4; ++rr) {
        int row = tile * 32 + rg * 16 + lk * 4 + rr;
        u16x4 v;
        #pragma unroll
        for (int n = 0; n < 4; ++n)
          v[n] = f2bf(acc[rg][n][rr]);
        *(u16x4*)(Yb + (size_t)row * 512 + w * 64 + lr * 4) = v;
      }
    }

    if (hn) {
      *(bf16x8*)(&A[p ^ 1][uoff0]) = cvt8v(a0, b0);
      *(bf16x8*)(&A[p ^ 1][uoff1]) = cvt8v(a1, b1);
      __syncthreads();
    }
    p ^= 1;
  }
}

__global__ void k_scan1(const int* __restrict__ deg, int* __restrict__ incl,
                        int* __restrict__ bsum) {
  __shared__ int sm[256];
  int i = blockIdx.x * 256 + threadIdx.x;
  int v = (i < NN) ? deg[i] : 0;
  sm[threadIdx.x] = v;
  __syncthreads();
  for (int s = 1; s < 256; s <<= 1) {
    int t = (threadIdx.x >= (unsigned)s) ? sm[threadIdx.x - s] : 0;
    __syncthreads();
    sm[threadIdx.x] += t;
    __syncthreads();
  }
  if (i < NN) incl[i] = sm[threadIdx.x];
  if (threadIdx.x == 255) bsum[blockIdx.x] = sm[255];
}

// fused scan2+scan3: every block scans the 196 block sums in LDS, takes its
// own exclusive prefix, then writes offs/cursor for its 256 nodes.
__global__ void k_scan23(const int* __restrict__ incl, const int* __restrict__ deg,
                         const int* __restrict__ bsum, int* __restrict__ offs,
                         int* __restrict__ cursor) {
  __shared__ int sm[256];
  int v = (threadIdx.x < 196) ? bsum[threadIdx.x] : 0;
  sm[threadIdx.x] = v;
  __syncthreads();
  for (int s = 1; s < 256; s <<= 1) {
    int t = (threadIdx.x >= (unsigned)s) ? sm[threadIdx.x - s] : 0;
    __syncthreads();
    sm[threadIdx.x] += t;
    __syncthreads();
  }
  int base = sm[blockIdx.x] - bsum[blockIdx.x];   // exclusive prefix at this block
  int i = blockIdx.x * 256 + threadIdx.x;
  if (i < NN) {
    int o = incl[i] - deg[i] + base;
    offs[i] = o;
    cursor[i] = o;
  }
}

__global__ void k_scatter(const int* __restrict__ Ai, const int* __restrict__ Aj,
                          int* __restrict__ cursor, int* __restrict__ edst) {
  int e = blockIdx.x * 256 + threadIdx.x;
  if (e < NE) {
    int p = atomicAdd(&cursor[Ai[e]], 1);
    edst[p] = Aj[e];
  }
}

// One wave per node: out[n] = deg[n]*(Y1b[n]+b) + sum_{CSR} Y2b[j].
// Yb column-permuted (64-col stripes): true col = (p&~63)|((p&3)<<4)|((p>>2)&15).
__global__ __launch_bounds__(256) void k_epi(
    const unsigned short* __restrict__ Yb, const int* __restrict__ offs,
    const int* __restrict__ deg, const int* __restrict__ edst,
    const float* __restrict__ bias, float* __restrict__ out) {
  __shared__ float sm[1024];
  int wid = threadIdx.x >> 6;
  int lane = threadIdx.x & 63;
  int n = blockIdx.x * 4 + wid;
  if (n >= NN) return;
  int o = offs[n];
  int c = deg[n];
  const unsigned short* Y2 = Yb + 256 + (size_t)lane * 4;
  f32x4 a0 = {0.f,0.f,0.f,0.f}, a1 = a0, a2 = a0, a3 = a0, a4 = a0, a5 = a0, a6 = a0, a7 = a0;
  int e = 0;
  for (; e + 8 <= c; e += 8) {
    int j0 = edst[o+e],   j1 = edst[o+e+1], j2 = edst[o+e+2], j3 = edst[o+e+3];
    int j4 = edst[o+e+4], j5 = edst[o+e+5], j6 = edst[o+e+6], j7 = edst[o+e+7];
    u16x4 v0 = *(const u16x4*)(Y2 + (size_t)j0 * 512);
    u16x4 v1 = *(const u16x4*)(Y2 + (size_t)j1 * 512);
    u16x4 v2 = *(const u16x4*)(Y2 + (size_t)j2 * 512);
    u16x4 v3 = *(const u16x4*)(Y2 + (size_t)j3 * 512);
    u16x4 v4 = *(const u16x4*)(Y2 + (size_t)j4 * 512);
    u16x4 v5 = *(const u16x4*)(Y2 + (size_t)j5 * 512);
    u16x4 v6 = *(const u16x4*)(Y2 + (size_t)j6 * 512);
    u16x4 v7 = *(const u16x4*)(Y2 + (size_t)j7 * 512);
    #pragma unroll
    for (int i = 0; i < 4; ++i) {
      a0[i] += bf2f(v0[i]); a1[i] += bf2f(v1[i]); a2[i] += bf2f(v2[i]); a3[i] += bf2f(v3[i]);
      a4[i] += bf2f(v4[i]); a5[i] += bf2f(v5[i]); a6[i] += bf2f(v6[i]); a7[i] += bf2f(v7[i]);
    }
  }
  if (e + 4 <= c) {
    int j0 = edst[o+e], j1 = edst[o+e+1], j2 = edst[o+e+2], j3 = edst[o+e+3];
    u16x4 v0 = *(const u16x4*)(Y2 + (size_t)j0 * 512);
    u16x4 v1 = *(const u16x4*)(Y2 + (size_t)j1 * 512);
    u16x4 v2 = *(const u16x4*)(Y2 + (size_t)j2 * 512);
    u16x4 v3 = *(const u16x4*)(Y2 + (size_t)j3 * 512);
    #pragma unroll
    for (int i = 0; i < 4; ++i) {
      a0[i] += bf2f(v0[i]); a1[i] += bf2f(v1[i]); a2[i] += bf2f(v2[i]); a3[i] += bf2f(v3[i]);
    }
    e += 4;
  }
  if (e + 2 <= c) {
    int j0 = edst[o+e], j1 = edst[o+e+1];
    u16x4 v0 = *(const u16x4*)(Y2 + (size_t)j0 * 512);
    u16x4 v1 = *(const u16x4*)(Y2 + (size_t)j1 * 512);
    #pragma unroll
    for (int i = 0; i < 4; ++i) { a0[i] += bf2f(v0[i]); a1[i] += bf2f(v1[i]); }
    e += 2;
  }
  if (e < c) {
    int j0 = edst[o+e];
    u16x4 v0 = *(const u16x4*)(Y2 + (size_t)j0 * 512);
    #pragma unroll
    for (int i = 0; i < 4; ++i) a0[i] += bf2f(v0[i]);
  }
  u16x4 y1 = *(const u16x4*)(Yb + (size_t)n * 512 + lane * 4);
  float dg = (float)c;
  float* Wm = sm + wid * 256;
  #pragma unroll
  for (int i = 0; i < 4; ++i) {
    int p = lane * 4 + i;                                        // permuted pos
    int tc = (p & ~63) | ((p & 3) << 4) | ((p >> 2) & 15);       // true col
    float as = ((a0[i] + a1[i]) + (a2[i] + a3[i])) + ((a4[i] + a5[i]) + (a6[i] + a7[i]));
    Wm[tc] = dg * (bf2f(y1[i]) + bias[tc]) + as;
  }
  asm volatile("s_waitcnt lgkmcnt(0)" ::: "memory");   // wave-lockstep unpermute
  f32x4 res = *(const f32x4*)(Wm + lane * 4);
  __builtin_nontemporal_store(res, (f32x4*)out + (size_t)n * 64 + lane);
}

extern "C" void kernel_launch(void* const* d_in, const int* in_sizes, int n_in,
                              void* d_out, int out_size, void* d_ws, size_t ws_size,
                              hipStream_t stream) {
  const float* x = (const float*)d_in[0];
  const float* W = (const float*)d_in[1];
  const float* b = (const float*)d_in[2];
  const int* Ai = (const int*)d_in[3];
  const int* Aj = (const int*)d_in[4];
  float* out = (float*)d_out;

  int* ip = (int*)d_ws;
  int* deg    = ip;            // 50048 (zeroed by k_wz, padded)
  int* incl   = ip + 50048;
  int* offs   = ip + 100096;
  int* cursor = ip + 150144;
  int* bsum   = ip + 200192;   // 256
  int* edst   = ip + 200448;   // 312576
  unsigned short* WbP = (unsigned short*)(ip + 513024);   // 131072 bf16 = 256KB
  unsigned short* Yb  = (unsigned short*)(ip + 578560);   // 50048*512 bf16 = 51.2MB

  k_wz<<<260, 256, 0, stream>>>(W, WbP, deg);
  k_gemm<<<256, 512, 0, stream>>>(x, WbP, Yb, Ai, deg);
  k_scan1<<<196, 256, 0, stream>>>(deg, incl, bsum);
  k_scan23<<<196, 256, 0, stream>>>(incl, deg, bsum, offs, cursor);
  k_scatter<<<1221, 256, 0, stream>>>(Ai, Aj, cursor, edst);
  k_epi<<<12500, 256, 0, stream>>>(Yb, offs, deg, edst, b, out);
}